// Round 1
// baseline (13075.159 us; speedup 1.0000x reference)
//
#include <hip/hip_runtime.h>
#include <cstdint>
#include <cstddef>

// ============================================================================
// PointerNet: encoder LSTM (B=512,S=256,D=2,H=256) + autoregressive pointer
// decode with jax.random.categorical (threefry2x32 partitionable, key 42).
// Output: int32 indices [512][256], trajectory-exact vs JAX reference.
//
// R5: kill the LDS-broadcast bottleneck. R4 was LDS-pipe bound: ~3200
// wave-uniform broadcast ds_read_b128 per CU per decoder step (~14.5 us of
// the 23 us step) delivering 16 useful bytes per ~11-cy instruction. Now
// each h/din slice is pulled with ONE per-lane ds_read_b128 (1 KB/inst) and
// broadcast via v_readlane -> SGPR operand of v_fma (free broadcast, off the
// LDS pipe). FMA order is bit-identical to R4 -> trajectory preserved.
// Also: barriers 5->4 per decoder step (din staging recomputes argmax from
// partV/partI instead of waiting on idxS), weight-loop unroll 2->4.
// ============================================================================

typedef float v4f __attribute__((ext_vector_type(4)));

#define WS_ENCW4_OFF  (2u << 20)                    // [256 k][256 u][4 g] f32
#define WS_DECWI4_OFF (3u << 20)
#define WS_DECWH4_OFF (4u << 20)
#define WS_ENCK4_OFF  (5u << 20)                    // [512 b][64 u4][256 s][4] f32
#define WS_NEEDED     ((size_t)(5u << 20) + (size_t)512 * 64 * 256 * 16)

__device__ __forceinline__ unsigned rotl32(unsigned x, int r) {
  return (x << r) | (x >> (32 - r));
}
__device__ __forceinline__ float sigm(float x) { return 1.f / (1.f + expf(-x)); }

// lane-broadcast via v_readlane: result lands in an SGPR and feeds v_fma as
// the (single allowed) scalar operand — no LDS-pipe instruction.
__device__ __forceinline__ float rl(float v, int lane) {
  return __int_as_float(__builtin_amdgcn_readlane(__float_as_int(v), lane));
}

// Threefry-2x32, 20 rounds (jax._src.prng schedule) — verified exact R1-R4.
__device__ __forceinline__ void tf2(unsigned k0, unsigned k1,
                                    unsigned& x0, unsigned& x1) {
  const unsigned k2 = k0 ^ k1 ^ 0x1BD11BDAu;
  x0 += k0; x1 += k1;
  x0 += x1; x1 = rotl32(x1, 13); x1 ^= x0;
  x0 += x1; x1 = rotl32(x1, 15); x1 ^= x0;
  x0 += x1; x1 = rotl32(x1, 26); x1 ^= x0;
  x0 += x1; x1 = rotl32(x1,  6); x1 ^= x0;
  x0 += k1; x1 += k2 + 1u;
  x0 += x1; x1 = rotl32(x1, 17); x1 ^= x0;
  x0 += x1; x1 = rotl32(x1, 29); x1 ^= x0;
  x0 += x1; x1 = rotl32(x1, 16); x1 ^= x0;
  x0 += x1; x1 = rotl32(x1, 24); x1 ^= x0;
  x0 += k2; x1 += k0 + 2u;
  x0 += x1; x1 = rotl32(x1, 13); x1 ^= x0;
  x0 += x1; x1 = rotl32(x1, 15); x1 ^= x0;
  x0 += x1; x1 = rotl32(x1, 26); x1 ^= x0;
  x0 += x1; x1 = rotl32(x1,  6); x1 ^= x0;
  x0 += k0; x1 += k1 + 3u;
  x0 += x1; x1 = rotl32(x1, 17); x1 ^= x0;
  x0 += x1; x1 = rotl32(x1, 29); x1 ^= x0;
  x0 += x1; x1 = rotl32(x1, 16); x1 ^= x0;
  x0 += x1; x1 = rotl32(x1, 24); x1 ^= x0;
  x0 += k1; x1 += k2 + 4u;
  x0 += x1; x1 = rotl32(x1, 13); x1 ^= x0;
  x0 += x1; x1 = rotl32(x1, 15); x1 ^= x0;
  x0 += x1; x1 = rotl32(x1, 26); x1 ^= x0;
  x0 += x1; x1 = rotl32(x1,  6); x1 ^= x0;
  x0 += k2; x1 += k0 + 5u;
}

// Repack W [1024 rows][256 k] row-major -> [k][u][gate] (float4 per (k,u)).
__global__ void repack_k(const float* __restrict__ eWh,
                         const float* __restrict__ dWi,
                         const float* __restrict__ dWh,
                         float* __restrict__ ws) {
  float* encW4 = (float*)((char*)ws + WS_ENCW4_OFF);
  float* decWi4 = (float*)((char*)ws + WS_DECWI4_OFF);
  float* decWh4 = (float*)((char*)ws + WS_DECWH4_OFF);
  const int n = blockIdx.x * blockDim.x + threadIdx.x;   // 65536 = 256k x 256u
  if (n >= 65536) return;
  const int k = n >> 8, u = n & 255;
#pragma unroll
  for (int g = 0; g < 4; ++g) {
    const int src = ((g << 8) + u) * 256 + k;
    const int dst = (n << 2) + g;
    encW4[dst] = eWh[src];
    decWi4[dst] = dWi[src];
    decWh4[dst] = dWh[src];
  }
}

__global__ void __launch_bounds__(1024)
ptrnet_kernel(const float* __restrict__ inp,    // [512][256][2]
              const float* __restrict__ eWi,    // [1024][2]
              const float* __restrict__ eBi, const float* __restrict__ eBh,
              const float* __restrict__ dBi, const float* __restrict__ dBh,
              int* __restrict__ out,            // [512][256]
              float* __restrict__ ws) {
  const int tid  = threadIdx.x;
  const int wave = tid >> 6, l = tid & 63;
  const int kq   = wave >> 2;               // K-quarter 0..3 (16 k4 each)
  const int uw   = wave & 3;                // u-slice 0..3
  const int uP   = (uw << 6) | l;           // this lane's unit in P1 (matmul)
  const int k4b  = kq << 4;
  const int bA   = tid >> 8;                // this thread's batch in P2/attn
  const int uA   = tid & 255;               // this thread's unit/score in P2/attn
  const int b0   = blockIdx.x << 2;
  const int bG   = b0 + bA;

  const v4f* encW4  = (const v4f*)((char*)ws + WS_ENCW4_OFF);
  const v4f* decWi4 = (const v4f*)((char*)ws + WS_DECWI4_OFF);
  const v4f* decWh4 = (const v4f*)((char*)ws + WS_DECWH4_OFF);
  v4f* encK4 = (v4f*)((char*)ws + WS_ENCK4_OFF);

  __shared__ __align__(16) float hsF[2][1024];   // h dbuf: [buf][b*256+u]
  __shared__ __align__(16) v4f dinV[256];        // dec_in [b][64 k4]
  __shared__ __align__(16) v4f red[16][256];     // partials [kq*4+b][u] (gates)
  __shared__ unsigned char maskC[4][256];
  __shared__ float partV[4][4];
  __shared__ int   partI[4][4];

  // per-lane slot of the 1 KB h/din slice this wave consumes:
  // lane m holds (batch m>>4, k4 = kq*16 + (m&15)) -> broadcast source lane
  // for (b, kk) is b*16+kk.
  const int hslot = ((l >> 4) << 6) | (kq << 4) | (l & 15);

  // ---- activation-thread constants (keyed by uA) ----
  const float ebi_ = eBi[uA] + eBh[uA];
  const float ebf_ = eBi[256 + uA] + eBh[256 + uA];
  const float ebg_ = eBi[512 + uA] + eBh[512 + uA];
  const float ebo_ = eBi[768 + uA] + eBh[768 + uA];
  const float wxi0 = eWi[2 * uA], wxi1 = eWi[2 * uA + 1];
  const float wxf0 = eWi[2 * (256 + uA)], wxf1 = eWi[2 * (256 + uA) + 1];
  const float wxg0 = eWi[2 * (512 + uA)], wxg1 = eWi[2 * (512 + uA) + 1];
  const float wxo0 = eWi[2 * (768 + uA)], wxo1 = eWi[2 * (768 + uA) + 1];

  hsF[0][tid] = 0.f;
  __syncthreads();

  float c = 0.f;        // cell state for (bG, uA) — register-resident throughout
  int p = 0;

  // ---------------- encoder: 256 steps ----------------
  for (int t = 0; t < 256; ++t) {
    // P1: Wh·h partials for this (kq, u) over all 4 batches.
    // h slice in registers (1 per-lane b128 read), broadcast via readlane.
    v4f a0 = (v4f)0.f, a1 = (v4f)0.f, a2 = (v4f)0.f, a3 = (v4f)0.f;
    {
      const v4f* Wp = encW4 + uP;
      const v4f hv = ((const v4f*)&hsF[p][0])[hslot];
#pragma unroll 4
      for (int kk = 0; kk < 16; ++kk) {
        const int k4 = k4b + kk;
        const v4f w0 = Wp[(k4 * 4 + 0) << 8];
        const v4f w1 = Wp[(k4 * 4 + 1) << 8];
        const v4f w2 = Wp[(k4 * 4 + 2) << 8];
        const v4f w3 = Wp[(k4 * 4 + 3) << 8];
        a0 += w0 * rl(hv.x, kk)      + w1 * rl(hv.y, kk)      + w2 * rl(hv.z, kk)      + w3 * rl(hv.w, kk);
        a1 += w0 * rl(hv.x, 16 + kk) + w1 * rl(hv.y, 16 + kk) + w2 * rl(hv.z, 16 + kk) + w3 * rl(hv.w, 16 + kk);
        a2 += w0 * rl(hv.x, 32 + kk) + w1 * rl(hv.y, 32 + kk) + w2 * rl(hv.z, 32 + kk) + w3 * rl(hv.w, 32 + kk);
        a3 += w0 * rl(hv.x, 48 + kk) + w1 * rl(hv.y, 48 + kk) + w2 * rl(hv.z, 48 + kk) + w3 * rl(hv.w, 48 + kk);
      }
    }
    red[(kq << 2) | 0][uP] = a0;
    red[(kq << 2) | 1][uP] = a1;
    red[(kq << 2) | 2][uP] = a2;
    red[(kq << 2) | 3][uP] = a3;
    __syncthreads();                              // S_B: partials ready
    // P2: activation for (bA, uA)
    const v4f gv = red[bA][uA] + red[4 + bA][uA] + red[8 + bA][uA] + red[12 + bA][uA];
    const float2 xv = *(const float2*)(inp + (((bG) << 8) + t) * 2);
    const float ai = gv.x + ebi_ + wxi0 * xv.x + wxi1 * xv.y;
    const float af = gv.y + ebf_ + wxf0 * xv.x + wxf1 * xv.y;
    const float ag = gv.z + ebg_ + wxg0 * xv.x + wxg1 * xv.y;
    const float ao = gv.w + ebo_ + wxo0 * xv.x + wxo1 * xv.y;
    const float iv = sigm(ai), fv = sigm(af), gva = tanhf(ag), ov = sigm(ao);
    c = fv * c + iv * gva;
    const float hn = ov * tanhf(c);
    hsF[p ^ 1][(bA << 8) | uA] = hn;
    ((float*)encK4)[(((bG << 6) + (uA >> 2)) << 10) + (t << 2) + (uA & 3)] = hn;
    __syncthreads();                              // S_C: new h ready
    p ^= 1;
  }

  // ---------------- decoder: 256 steps ----------------
  const float dbi_ = dBi[uA] + dBh[uA];
  const float dbf_ = dBi[256 + uA] + dBh[256 + uA];
  const float dbg_ = dBi[512 + uA] + dBh[512 + uA];
  const float dbo_ = dBi[768 + uA] + dBh[768 + uA];
  const float NEG_INF = __int_as_float((int)0xff800000);

  maskC[bA][uA] = 0;
  if (tid < 256) dinV[tid] = (v4f)0.f;            // dec_in(t=0) = 0
  __syncthreads();

  for (int t = 0; t < 256; ++t) {
    // P1: Wh·h + Wi·din partials; h/din slices in registers, readlane bcast
    v4f a0 = (v4f)0.f, a1 = (v4f)0.f, a2 = (v4f)0.f, a3 = (v4f)0.f;
    {
      const v4f* Wh = decWh4 + uP;
      const v4f hv = ((const v4f*)&hsF[p][0])[hslot];
#pragma unroll 4
      for (int kk = 0; kk < 16; ++kk) {
        const int k4 = k4b + kk;
        const v4f w0 = Wh[(k4 * 4 + 0) << 8];
        const v4f w1 = Wh[(k4 * 4 + 1) << 8];
        const v4f w2 = Wh[(k4 * 4 + 2) << 8];
        const v4f w3 = Wh[(k4 * 4 + 3) << 8];
        a0 += w0 * rl(hv.x, kk)      + w1 * rl(hv.y, kk)      + w2 * rl(hv.z, kk)      + w3 * rl(hv.w, kk);
        a1 += w0 * rl(hv.x, 16 + kk) + w1 * rl(hv.y, 16 + kk) + w2 * rl(hv.z, 16 + kk) + w3 * rl(hv.w, 16 + kk);
        a2 += w0 * rl(hv.x, 32 + kk) + w1 * rl(hv.y, 32 + kk) + w2 * rl(hv.z, 32 + kk) + w3 * rl(hv.w, 32 + kk);
        a3 += w0 * rl(hv.x, 48 + kk) + w1 * rl(hv.y, 48 + kk) + w2 * rl(hv.z, 48 + kk) + w3 * rl(hv.w, 48 + kk);
      }
    }
    {
      const v4f* Wi = decWi4 + uP;
      const v4f dv = dinV[hslot];
#pragma unroll 4
      for (int kk = 0; kk < 16; ++kk) {
        const int k4 = k4b + kk;
        const v4f w0 = Wi[(k4 * 4 + 0) << 8];
        const v4f w1 = Wi[(k4 * 4 + 1) << 8];
        const v4f w2 = Wi[(k4 * 4 + 2) << 8];
        const v4f w3 = Wi[(k4 * 4 + 3) << 8];
        a0 += w0 * rl(dv.x, kk)      + w1 * rl(dv.y, kk)      + w2 * rl(dv.z, kk)      + w3 * rl(dv.w, kk);
        a1 += w0 * rl(dv.x, 16 + kk) + w1 * rl(dv.y, 16 + kk) + w2 * rl(dv.z, 16 + kk) + w3 * rl(dv.w, 16 + kk);
        a2 += w0 * rl(dv.x, 32 + kk) + w1 * rl(dv.y, 32 + kk) + w2 * rl(dv.z, 32 + kk) + w3 * rl(dv.w, 32 + kk);
        a3 += w0 * rl(dv.x, 48 + kk) + w1 * rl(dv.y, 48 + kk) + w2 * rl(dv.z, 48 + kk) + w3 * rl(dv.w, 48 + kk);
      }
    }
    red[(kq << 2) | 0][uP] = a0;
    red[(kq << 2) | 1][uP] = a1;
    red[(kq << 2) | 2][uP] = a2;
    red[(kq << 2) | 3][uP] = a3;
    __syncthreads();                              // S_B: partials ready

    // P2: activation for (bA, uA)
    const v4f gv = red[bA][uA] + red[4 + bA][uA] + red[8 + bA][uA] + red[12 + bA][uA];
    const float ai = gv.x + dbi_;
    const float af = gv.y + dbf_;
    const float ag = gv.z + dbg_;
    const float ao = gv.w + dbo_;
    const float iv = sigm(ai), fv = sigm(af), gva = tanhf(ag), ov = sigm(ao);
    c = fv * c + iv * gva;
    const float hn = ov * tanhf(c);
    hsF[p ^ 1][(bA << 8) | uA] = hn;
    __syncthreads();                              // S_C: new h ready
    p ^= 1;

    // attention + gumbel sampling: thread (bA, s=uA)
    const int s = uA;
    const int masked = maskC[bA][s];
    // per-lane h slice: lane l holds h[bA][4l..4l+3]. Must be loaded by ALL
    // lanes (readlane sources) — pin it so the compiler can't sink it into
    // the divergent if-block below.
    v4f hvA = ((const v4f*)&hsF[p][0])[(bA << 6) | l];
    asm volatile("" : "+v"(hvA));
    float sc = 0.f;
    if (!masked) {
      const v4f* E = encK4 + (bG << 14) + s;
#pragma unroll 4
      for (int k4 = 0; k4 < 64; ++k4) {
        const v4f ev = E[k4 << 8];
        sc += ev.x * rl(hvA.x, k4) + ev.y * rl(hvA.y, k4)
            + ev.z * rl(hvA.z, k4) + ev.w * rl(hvA.w, k4);
      }
    }
    // threefry2x32 partitionable: key_t = tf2(key42; 0,t); bits = x0^x1
    unsigned bits;
    {
      unsigned kk0 = 0u, kk1 = (unsigned)t;
      tf2(0u, 42u, kk0, kk1);
      unsigned y0 = 0u, y1 = (unsigned)((bG << 8) + s);
      tf2(kk0, kk1, y0, y1);
      bits = y0 ^ y1;
    }
    const float fr = __uint_as_float((bits >> 9) | 0x3f800000u) - 1.0f;
    const float uu = (fr > 0.f) ? fr : 1.17549435e-38f;
    const float gum = -logf(-logf(uu));
    float bv = masked ? NEG_INF : (sc + gum);
    int bi = s;
    // wave argmax, first-index tie-break (matches jnp.argmax)
#pragma unroll
    for (int off = 32; off; off >>= 1) {
      const float ov2 = __shfl_xor(bv, off, 64);
      const int oi2 = __shfl_xor(bi, off, 64);
      if (ov2 > bv || (ov2 == bv && oi2 < bi)) { bv = ov2; bi = oi2; }
    }
    if (l == 0) { partV[bA][uw] = bv; partI[bA][uw] = bi; }
    __syncthreads();                              // S_D: wave partials ready

    // final cross-chunk argmax, computed redundantly by all threads of batch
    float v = partV[bA][0]; int fi = partI[bA][0];
#pragma unroll
    for (int j = 1; j < 4; ++j) {
      const float vj = partV[bA][j];
      if (vj > v) { v = vj; fi = partI[bA][j]; }   // strict > keeps lowest s
    }
    if (uA == 0) out[(bG << 8) + t] = fi;
    if (uA == fi) maskC[bA][uA] = 1;
    // stage next dec_in directly: staging thread recomputes argmax for ITS
    // batch bb from partV/partI (no idxS round-trip, saves one barrier)
    if (tid < 256) {
      const int bb = tid >> 6, k4s = tid & 63;
      float v2 = partV[bb][0]; int fib = partI[bb][0];
#pragma unroll
      for (int j = 1; j < 4; ++j) {
        const float vj = partV[bb][j];
        if (vj > v2) { v2 = vj; fib = partI[bb][j]; }
      }
      dinV[tid] = encK4[((((b0 + bb) << 6) | k4s) << 8) + fib];
    }
    __syncthreads();                              // S_A: din/mask ready
  }
}

extern "C" void kernel_launch(void* const* d_in, const int* in_sizes, int n_in,
                              void* d_out, int out_size, void* d_ws, size_t ws_size,
                              hipStream_t stream) {
  (void)in_sizes; (void)n_in; (void)out_size;
  if (ws_size < WS_NEEDED) return;   // need ~139 MB scratch

  const float* inp = (const float*)d_in[0];
  const float* eWi = (const float*)d_in[1];
  const float* eWh = (const float*)d_in[2];
  const float* eBi = (const float*)d_in[3];
  const float* eBh = (const float*)d_in[4];
  const float* dWi = (const float*)d_in[5];
  const float* dWh = (const float*)d_in[6];
  const float* dBi = (const float*)d_in[7];
  const float* dBh = (const float*)d_in[8];
  int* out = (int*)d_out;
  float* wsf = (float*)d_ws;

  hipLaunchKernelGGL(repack_k, dim3(256), dim3(256), 0, stream, eWh, dWi, dWh, wsf);
  hipLaunchKernelGGL(ptrnet_kernel, dim3(128), dim3(1024), 0, stream,
                     inp, eWi, eBi, eBh, dBi, dBh, out, wsf);
}